// Round 6
// baseline (346.766 us; speedup 1.0000x reference)
//
#include <hip/hip_runtime.h>
#include <hip/hip_bf16.h>

// B=4, S=2048, D=1024, P=1024 causal self-attention, bf16 MFMA pipeline.
// Round 6: hybrid operand delivery. A staged via global_load_lds (ping-pong,
// 32 KB LDS); B fragments loaded DIRECTLY global->VGPR (k-contiguous B^T rows
// = one dwordx4 per lane), double-buffered across the barrier. Cuts DS-pipe
// traffic 2x (the measured bottleneck) and pipelines B as plain VMEM.

#define BDIM 4
#define SDIM 2048
#define DDIM 1024
#define PDIM 1024

typedef __attribute__((ext_vector_type(8))) short bf16x8;
typedef __attribute__((ext_vector_type(4))) float f32x4;

// ---------- helpers ----------
__device__ __forceinline__ unsigned short f2bf(float f) {
    union { float f; unsigned int u; } v; v.f = f;
    unsigned int u = v.u;
    unsigned int r = (u + 0x7fffu + ((u >> 16) & 1u)) >> 16;
    return (unsigned short)r;
}

__device__ __forceinline__ float bf2f(unsigned short h) {
    union { unsigned int u; float f; } v;
    v.u = ((unsigned int)h) << 16;
    return v.f;
}

__device__ __forceinline__ void async16(const unsigned short* g, unsigned short* l) {
    __builtin_amdgcn_global_load_lds(
        (const __attribute__((address_space(1))) unsigned int*)g,
        (__attribute__((address_space(3))) unsigned int*)l,
        16, 0, 0);
}

__device__ __forceinline__ void storeC(float* C, size_t idx, float v) { C[idx] = v; }
__device__ __forceinline__ void storeC(unsigned short* C, size_t idx, float v) { C[idx] = f2bf(v); }

// ---------- fused prep: cast x (fp32->bf16) + transpose/cast W ----------
__global__ __launch_bounds__(256) void prep_kernel(const float* __restrict__ x,
                                                   const float* __restrict__ W0,
                                                   const float* __restrict__ W1,
                                                   const float* __restrict__ W2,
                                                   unsigned short* __restrict__ Xb,
                                                   unsigned short* __restrict__ WT) {
    int bid = blockIdx.x;
    if (bid < 4096) {
        size_t i = (size_t)bid * 256 + threadIdx.x;
        float4 a = ((const float4*)x)[2 * i];
        float4 b = ((const float4*)x)[2 * i + 1];
        bf16x8 o;
        o[0] = (short)f2bf(a.x); o[1] = (short)f2bf(a.y);
        o[2] = (short)f2bf(a.z); o[3] = (short)f2bf(a.w);
        o[4] = (short)f2bf(b.x); o[5] = (short)f2bf(b.y);
        o[6] = (short)f2bf(b.z); o[7] = (short)f2bf(b.w);
        ((bf16x8*)Xb)[i] = o;
    } else {
        int idx = bid - 4096;
        int wz = idx >> 10;
        int t = idx & 1023;
        const float* W = (wz == 0) ? W0 : (wz == 1) ? W1 : W2;
        unsigned short* Tz = WT + (size_t)wz * DDIM * PDIM;
        __shared__ float tle[32][33];
        int c0 = (t & 31) * 32, r0 = (t >> 5) * 32;
        int tx = threadIdx.x & 31, ty = threadIdx.x >> 5;
        for (int i = ty; i < 32; i += 8)
            tle[i][tx] = W[(size_t)(r0 + i) * PDIM + c0 + tx];
        __syncthreads();
        for (int i = ty; i < 32; i += 8)
            Tz[(size_t)(c0 + i) * DDIM + r0 + tx] = f2bf(tle[tx][i]);
    }
}

// ---------- hybrid BK=64 GEMM: C[M][N] = alpha * A[M][K] @ Bt[N][K]^T ----------
// A: XOR-swizzled LDS (chunk c of row r at c^(r&7)), ping-pong 2x16 KB.
// B: direct global->VGPR dwordx4 fragments, double-buffered across barrier.
// MODE 0: fused QKV (tn<1024 -> Q, <2048 -> Kb, else VT transposed via LDS).
// MODE 1: causal scores, packed lower-triangle grid; skips masked stores.
// MODE 2: PV, K clamped at tm+BM (ns always even).
template <int LDA, int LDB, int LDC, int KMAX, int MODE, typename CT>
__global__ __launch_bounds__(256) void gemm_bt(
    const unsigned short* __restrict__ A0, const unsigned short* __restrict__ A1,
    long long sA,
    const unsigned short* __restrict__ B0, long long sB,
    CT* __restrict__ C0, CT* __restrict__ C1, long long sC,
    unsigned short* __restrict__ Kb, unsigned short* __restrict__ VT,
    float alpha) {
    const int BM = 128, BN = 128, BK = 64;
    const int ABUF = BM * BK;  // 8192 shorts = 16 KB per buffer
    __shared__ __attribute__((aligned(16))) unsigned short smem[2 * ABUF];  // 32 KB

    int tm, tn;
    if (MODE == 1) {
        int i = blockIdx.x;
        int t = (int)((sqrtf(8.f * i + 1.f) - 1.f) * 0.5f);
        if ((t + 1) * (t + 2) / 2 <= i) t++;
        if (t * (t + 1) / 2 > i) t--;
        tm = t * BM;
        tn = (i - t * (t + 1) / 2) * BN;
    } else {
        tm = blockIdx.y * BM;
        tn = blockIdx.x * BN;
    }
    int kend = (MODE == 2) ? min(KMAX, tm + BM) : KMAX;

    int z = blockIdx.z;
    const unsigned short* A = (z < 2 ? A0 : A1) + (long long)(z & 1) * sA;
    const unsigned short* Bt = B0 + (long long)z * sB;
    CT* C = (z < 2 ? C0 : C1) + (long long)(z & 1) * sC;

    int tid  = threadIdx.x;
    int lane = tid & 63;
    int wave = tid >> 6;
    int wr   = (wave >> 1) * 64;
    int wc   = (wave & 1) * 64;
    int quad = lane >> 4;
    int l16  = lane & 15;
    int rsw  = l16 & 7;

    f32x4 acc[4][4] = {};

    // A staging: thread -> (row = tid>>3 (+32/pass), stored chunk = tid&7)
    int srow = tid >> 3;
    int scol = ((tid & 7) ^ (srow & 7)) * 8;
    const unsigned short* Ag = A + (size_t)(tm + srow) * LDA + scol;
    // B fragment base: lane reads row (tn+wc+j*16+l16), k-chunk quad*8 (+k0+s*32)
    const unsigned short* Bg = Bt + (size_t)(tn + wc + l16) * LDB + quad * 8;

    auto issueA = [&](int k0, int buf) {
        unsigned short* la = smem + buf * ABUF + tid * 8;
        async16(Ag + k0, la);
        async16(Ag + k0 + 32 * LDA, la + 2048);
        async16(Ag + k0 + 64 * LDA, la + 4096);
        async16(Ag + k0 + 96 * LDA, la + 6144);
    };

    bf16x8 bb[2][2][4];  // [buf][s][j] -- 64 VGPRs

    auto loadB = [&](int buf, int k0) {
#pragma unroll
        for (int s = 0; s < 2; s++)
#pragma unroll
            for (int j = 0; j < 4; j++)
                bb[buf][s][j] = *(const bf16x8*)(Bg + (size_t)j * 16 * LDB + k0 + s * 32);
    };

    auto compute = [&](int abuf, int bbuf) {
        const unsigned short* As = smem + abuf * ABUF;
#pragma unroll
        for (int s = 0; s < 2; s++) {
            int chunk = ((s * 4 + quad) ^ rsw) * 8;
            bf16x8 af[4];
#pragma unroll
            for (int i = 0; i < 4; i++)
                af[i] = *(const bf16x8*)(As + (wr + i * 16 + l16) * BK + chunk);
#pragma unroll
            for (int i = 0; i < 4; i++)
#pragma unroll
                for (int j = 0; j < 4; j++)
                    acc[i][j] = __builtin_amdgcn_mfma_f32_16x16x32_bf16(
                        af[i], bb[bbuf][s][j], acc[i][j], 0, 0, 0);
        }
    };

    if constexpr (MODE != 2) {
        constexpr int NS = KMAX / BK;
        issueA(0, 0);
        loadB(0, 0);
#pragma unroll
        for (int i = 0; i < NS; i++) {
            __syncthreads();  // drains A-lds + B loads issued last iter
            if (i + 1 < NS) { issueA((i + 1) * BK, (i + 1) & 1); loadB((i + 1) & 1, (i + 1) * BK); }
            compute(i & 1, i & 1);
        }
    } else {
        int ns = kend / BK;  // = (tm+128)/64, always even, >= 2
        issueA(0, 0);
        loadB(0, 0);
        for (int i = 0; i < ns; i += 2) {
            __syncthreads();
            issueA((i + 1) * BK, 1);
            loadB(1, (i + 1) * BK);
            compute(0, 0);
            __syncthreads();
            if (i + 2 < ns) { issueA((i + 2) * BK, 0); loadB(0, (i + 2) * BK); }
            compute(1, 1);
        }
    }

    // ---------------- epilogue (C/D layout: col=lane&15, row=quad*4+reg) ----------------
    if constexpr (MODE == 0) {
        if (tn < 2048) {
            unsigned short* D = (tn < 1024 ? (unsigned short*)C0 : Kb);
            int cbase = tn & 1023;
#pragma unroll
            for (int i = 0; i < 4; i++) {
                int r0 = tm + wr + i * 16 + quad * 4;
#pragma unroll
                for (int j = 0; j < 4; j++) {
                    int c = cbase + wc + j * 16 + l16;
#pragma unroll
                    for (int rr = 0; rr < 4; rr++)
                        D[(size_t)(r0 + rr) * 1024 + c] = f2bf(acc[i][j][rr]);
                }
            }
        } else {
            // V region: transposed write via LDS (4 passes of 32 p-columns)
            int b = tm >> 11;
            int s0 = tm & 2047;
            unsigned short* VTb = VT + (size_t)b * (PDIM * SDIM)
                                     + (size_t)(tn - 2048) * SDIM + s0;
            const int TP = 136;
            unsigned short* T = smem;  // 32x136 shorts = 8.7 KB, reuses buf0
            __syncthreads();
#pragma unroll
            for (int p = 0; p < 4; p++) {
                int jbase = -1;
                if (wc == 0 && p == 0) jbase = 0;
                if (wc == 0 && p == 1) jbase = 2;
                if (wc == 64 && p == 2) jbase = 0;
                if (wc == 64 && p == 3) jbase = 2;
                if (jbase >= 0) {
#pragma unroll
                    for (int jj = 0; jj < 2; jj++) {
                        int j = jbase + jj;
                        int c = (wc + j * 16 + l16) - 32 * p;  // 0..31
#pragma unroll
                        for (int i = 0; i < 4; i++) {
                            int r = wr + i * 16 + quad * 4;
                            ushort4 w;
                            w.x = f2bf(acc[i][j][0]); w.y = f2bf(acc[i][j][1]);
                            w.z = f2bf(acc[i][j][2]); w.w = f2bf(acc[i][j][3]);
                            *(ushort4*)(T + c * TP + r) = w;
                        }
                    }
                }
                __syncthreads();
                {
                    int lr = tid >> 3;
                    int ck = (tid & 7) * 16;
                    bf16x8 u0 = *(const bf16x8*)(T + lr * TP + ck);
                    bf16x8 u1 = *(const bf16x8*)(T + lr * TP + ck + 8);
                    unsigned short* dst = VTb + (size_t)(32 * p + lr) * SDIM + ck;
                    *(bf16x8*)(dst) = u0;
                    *(bf16x8*)(dst + 8) = u1;
                }
                __syncthreads();
            }
        }
    } else {
#pragma unroll
        for (int i = 0; i < 4; i++) {
            int r0 = tm + wr + i * 16 + quad * 4;
#pragma unroll
            for (int j = 0; j < 4; j++) {
                int c = tn + wc + j * 16 + l16;
#pragma unroll
                for (int rr = 0; rr < 4; rr++) {
                    int r = r0 + rr;
                    if (MODE == 1 && c > r) continue;  // masked: never read downstream
                    storeC(C, (size_t)r * LDC + c, acc[i][j][rr] * alpha);
                }
            }
        }
    }
}

// ---------- in-place causal softmax on bf16 S ----------
__global__ __launch_bounds__(256) void softmax_causal(unsigned short* __restrict__ S01,
                                                      unsigned short* __restrict__ S23,
                                                      long long sS) {
    int row = blockIdx.x;
    int b = blockIdx.y;
    unsigned short* srow = (b < 2 ? S01 : S23) + (long long)(b & 1) * sS + (size_t)row * SDIM;
    int tid = threadIdx.x;
    int j0 = tid * 8;
    int valid = row + 1;
    int bound = ((row >> 7) + 1) << 7;
    bool active = j0 < valid;
    __shared__ float red[4];

    float f[8];
    if (active) {
        bf16x8 v8 = *(const bf16x8*)(srow + j0);
#pragma unroll
        for (int i = 0; i < 8; i++) f[i] = bf2f((unsigned short)v8[i]);
    }

    float m = -1e30f;
    if (active) {
#pragma unroll
        for (int i = 0; i < 8; i++) if (j0 + i < valid) m = fmaxf(m, f[i]);
    }
#pragma unroll
    for (int o = 32; o; o >>= 1) m = fmaxf(m, __shfl_xor(m, o, 64));
    if ((tid & 63) == 0) red[tid >> 6] = m;
    __syncthreads();
    m = fmaxf(fmaxf(red[0], red[1]), fmaxf(red[2], red[3]));
    __syncthreads();

    float e[8] = {0.f, 0.f, 0.f, 0.f, 0.f, 0.f, 0.f, 0.f};
    float l = 0.f;
    if (active) {
#pragma unroll
        for (int i = 0; i < 8; i++) {
            e[i] = (j0 + i < valid) ? __expf(f[i] - m) : 0.f;
            l += e[i];
        }
    }
#pragma unroll
    for (int o = 32; o; o >>= 1) l += __shfl_xor(l, o, 64);
    if ((tid & 63) == 0) red[tid >> 6] = l;
    __syncthreads();
    l = red[0] + red[1] + red[2] + red[3];
    float inv = 1.0f / l;

    if (j0 < bound) {
        bf16x8 o8;
#pragma unroll
        for (int i = 0; i < 8; i++) o8[i] = (short)f2bf(e[i] * inv);
        *(bf16x8*)(srow + j0) = o8;
    }
}

// ---------- host ----------
extern "C" void kernel_launch(void* const* d_in, const int* in_sizes, int n_in,
                              void* d_out, int out_size, void* d_ws, size_t ws_size,
                              hipStream_t stream) {
    const float* x  = (const float*)d_in[0];
    const float* Wq = (const float*)d_in[1];
    const float* Wk = (const float*)d_in[2];
    const float* Wv = (const float*)d_in[3];
    float* out = (float*)d_out;

    const size_t MS = (size_t)BDIM * SDIM;        // 8192
    const long long SS = (long long)SDIM * SDIM;  // per-batch score elems
    char* ws = (char*)d_ws;
    size_t off = 0;
    // S01 aliases Xb (Xb dead after QKV GEMM).
    unsigned short* Xb   = (unsigned short*)(ws + off);
    unsigned short* S01  = Xb;                          off += MS * DDIM * 2;           // 16 MB
    unsigned short* WT   = (unsigned short*)(ws + off); off += 3ull * DDIM * PDIM * 2;  // 6 MB
    unsigned short* Q    = (unsigned short*)(ws + off); off += MS * PDIM * 2;           // 16 MB
    unsigned short* Kb   = (unsigned short*)(ws + off); off += MS * PDIM * 2;           // 16 MB
    unsigned short* VT   = (unsigned short*)(ws + off); off += MS * PDIM * 2;           // 16 MB
    unsigned short* S23  = (unsigned short*)(ws + off); off += 2ull * SS * 2;           // 16 MB
    // total ~86 MB

    // 1. fused prep: cast x -> bf16  +  transpose/cast weights
    prep_kernel<<<4096 + 3072, 256, 0, stream>>>(x, Wq, Wk, Wv, Xb, WT);

    // 2. fused QKV projection -> Q, Kb, VT(transposed)   (1536 blocks)
    gemm_bt<DDIM, DDIM, PDIM, DDIM, 0, unsigned short>
        <<<dim3(3 * PDIM / 128, MS / 128, 1), 256, 0, stream>>>(
        Xb, Xb, 0, WT, 0, Q, Q, 0, Kb, VT, 1.0f);

    const long long sQ = (long long)SDIM * PDIM;   // per-batch Q/K/VT stride
    const float alpha = 1.0f / 32.0f;              // 1/sqrt(P)

    // 3. scores: packed lower-triangle grid (136 tiles) x 4 batches
    gemm_bt<PDIM, PDIM, SDIM, PDIM, 1, unsigned short>
        <<<dim3(136, 1, BDIM), 256, 0, stream>>>(
        Q, Q + 2 * sQ, sQ, Kb, sQ, S01, S23, SS, nullptr, nullptr, alpha);

    // 4. in-place softmax (S -> P, bf16)
    softmax_causal<<<dim3(SDIM, BDIM), 256, 0, stream>>>(S01, S23, SS);

    // 5. PV: out_b = P_b @ VT_b^T with causal K clamp
    const long long sOut = (long long)SDIM * PDIM;
    gemm_bt<SDIM, SDIM, PDIM, SDIM, 2, float>
        <<<dim3(PDIM / 128, SDIM / 128, BDIM), 256, 0, stream>>>(
        S01, S23, SS, VT, sQ, out, out + 2 * sOut, sOut, nullptr, nullptr, 1.0f);
}

// Round 7
// 229.627 us; speedup vs baseline: 1.5101x; 1.5101x over previous
//
#include <hip/hip_runtime.h>
#include <hip/hip_bf16.h>

// B=4, S=2048, D=1024, P=1024 causal self-attention, bf16 MFMA pipeline.
// Round 7: revert R6's direct-B-loads (LLVM sank them -> serial latency).
// New core: A double-buffered + B single-buffered in LDS (48 KB -> 3
// blocks/CU), two-barrier ktile (sync1 drain; B frags LDS->regs; sync2
// frees B buffer; issue next A+B; compute with loads in flight).
// Scores/PV grids now fully co-resident (<=768 slots); PV launches big
// tiles first (reversed y).

#define BDIM 4
#define SDIM 2048
#define DDIM 1024
#define PDIM 1024

typedef __attribute__((ext_vector_type(8))) short bf16x8;
typedef __attribute__((ext_vector_type(4))) float f32x4;

// ---------- helpers ----------
__device__ __forceinline__ unsigned short f2bf(float f) {
    union { float f; unsigned int u; } v; v.f = f;
    unsigned int u = v.u;
    unsigned int r = (u + 0x7fffu + ((u >> 16) & 1u)) >> 16;
    return (unsigned short)r;
}

__device__ __forceinline__ float bf2f(unsigned short h) {
    union { unsigned int u; float f; } v;
    v.u = ((unsigned int)h) << 16;
    return v.f;
}

__device__ __forceinline__ void async16(const unsigned short* g, unsigned short* l) {
    __builtin_amdgcn_global_load_lds(
        (const __attribute__((address_space(1))) unsigned int*)g,
        (__attribute__((address_space(3))) unsigned int*)l,
        16, 0, 0);
}

__device__ __forceinline__ void storeC(float* C, size_t idx, float v) { C[idx] = v; }
__device__ __forceinline__ void storeC(unsigned short* C, size_t idx, float v) { C[idx] = f2bf(v); }

// ---------- fused prep: cast x (fp32->bf16) + transpose/cast W ----------
__global__ __launch_bounds__(256) void prep_kernel(const float* __restrict__ x,
                                                   const float* __restrict__ W0,
                                                   const float* __restrict__ W1,
                                                   const float* __restrict__ W2,
                                                   unsigned short* __restrict__ Xb,
                                                   unsigned short* __restrict__ WT) {
    int bid = blockIdx.x;
    if (bid < 4096) {
        size_t i = (size_t)bid * 256 + threadIdx.x;
        float4 a = ((const float4*)x)[2 * i];
        float4 b = ((const float4*)x)[2 * i + 1];
        bf16x8 o;
        o[0] = (short)f2bf(a.x); o[1] = (short)f2bf(a.y);
        o[2] = (short)f2bf(a.z); o[3] = (short)f2bf(a.w);
        o[4] = (short)f2bf(b.x); o[5] = (short)f2bf(b.y);
        o[6] = (short)f2bf(b.z); o[7] = (short)f2bf(b.w);
        ((bf16x8*)Xb)[i] = o;
    } else {
        int idx = bid - 4096;
        int wz = idx >> 10;
        int t = idx & 1023;
        const float* W = (wz == 0) ? W0 : (wz == 1) ? W1 : W2;
        unsigned short* Tz = WT + (size_t)wz * DDIM * PDIM;
        __shared__ float tle[32][33];
        int c0 = (t & 31) * 32, r0 = (t >> 5) * 32;
        int tx = threadIdx.x & 31, ty = threadIdx.x >> 5;
        for (int i = ty; i < 32; i += 8)
            tle[i][tx] = W[(size_t)(r0 + i) * PDIM + c0 + tx];
        __syncthreads();
        for (int i = ty; i < 32; i += 8)
            Tz[(size_t)(c0 + i) * DDIM + r0 + tx] = f2bf(tle[tx][i]);
    }
}

// ---------- BK=64 GEMM: C[M][N] = alpha * A[M][K] @ Bt[N][K]^T ----------
// XOR-swizzled LDS (chunk c of row r at c^(r&7)) -> conflict-free ds_read_b128.
// A: ping-pong 2x16 KB; B: single 16 KB buffer (total 48 KB -> 3 blocks/CU).
// ktile: sync1; B frags->regs; sync2; issue A/B for i+1; compute.
// MODE 0: fused QKV (tn<1024 -> Q, <2048 -> Kb, else VT transposed via LDS).
// MODE 1: causal scores, packed lower-triangle grid; skips masked stores.
// MODE 2: PV, K clamped at tm+BM; reversed-y launch order (big tiles first).
template <int LDA, int LDB, int LDC, int KMAX, int MODE, typename CT>
__global__ __launch_bounds__(256) void gemm_bt(
    const unsigned short* __restrict__ A0, const unsigned short* __restrict__ A1,
    long long sA,
    const unsigned short* __restrict__ B0, long long sB,
    CT* __restrict__ C0, CT* __restrict__ C1, long long sC,
    unsigned short* __restrict__ Kb, unsigned short* __restrict__ VT,
    float alpha) {
    const int BM = 128, BN = 128, BK = 64;
    const int ABUF = BM * BK;  // 8192 shorts = 16 KB
    __shared__ __attribute__((aligned(16))) unsigned short smem[2 * ABUF + BN * BK];  // 48 KB
    unsigned short* BsBuf = smem + 2 * ABUF;

    int tm, tn;
    if (MODE == 1) {
        int i = blockIdx.x;
        int t = (int)((sqrtf(8.f * i + 1.f) - 1.f) * 0.5f);
        if ((t + 1) * (t + 2) / 2 <= i) t++;
        if (t * (t + 1) / 2 > i) t--;
        tm = t * BM;
        tn = (i - t * (t + 1) / 2) * BN;
    } else if (MODE == 2) {
        tm = ((int)gridDim.y - 1 - (int)blockIdx.y) * BM;  // big-ns tiles first
        tn = blockIdx.x * BN;
    } else {
        tm = blockIdx.y * BM;
        tn = blockIdx.x * BN;
    }
    int kend = (MODE == 2) ? min(KMAX, tm + BM) : KMAX;

    int z = blockIdx.z;
    const unsigned short* A = (z < 2 ? A0 : A1) + (long long)(z & 1) * sA;
    const unsigned short* Bt = B0 + (long long)z * sB;
    CT* C = (z < 2 ? C0 : C1) + (long long)(z & 1) * sC;

    int tid  = threadIdx.x;
    int lane = tid & 63;
    int wave = tid >> 6;
    int wr   = (wave >> 1) * 64;
    int wc   = (wave & 1) * 64;
    int quad = lane >> 4;
    int l16  = lane & 15;
    int rsw  = l16 & 7;

    f32x4 acc[4][4] = {};

    // staging: thread -> (row = tid>>3 (+32/pass), stored chunk = tid&7)
    int srow = tid >> 3;
    int scol = ((tid & 7) ^ (srow & 7)) * 8;
    const unsigned short* Ag = A + (size_t)(tm + srow) * LDA + scol;
    const unsigned short* Bg = Bt + (size_t)(tn + srow) * LDB + scol;

    auto issueA = [&](int k0, int buf) {
        unsigned short* la = smem + buf * ABUF + tid * 8;
        async16(Ag + k0, la);
        async16(Ag + k0 + 32 * LDA, la + 2048);
        async16(Ag + k0 + 64 * LDA, la + 4096);
        async16(Ag + k0 + 96 * LDA, la + 6144);
    };
    auto issueB = [&](int k0) {
        unsigned short* lb = BsBuf + tid * 8;
        async16(Bg + k0, lb);
        async16(Bg + k0 + 32 * LDB, lb + 2048);
        async16(Bg + k0 + 64 * LDB, lb + 4096);
        async16(Bg + k0 + 96 * LDB, lb + 6144);
    };

    auto kbody = [&](int i, int ns) {
        __syncthreads();  // sync1: drains A[i&1] + B (in flight since last iter)
        bf16x8 bf[2][4];
#pragma unroll
        for (int s = 0; s < 2; s++)
#pragma unroll
            for (int j = 0; j < 4; j++)
                bf[s][j] = *(const bf16x8*)(BsBuf + (wc + j * 16 + l16) * BK
                                                  + ((s * 4 + quad) ^ rsw) * 8);
        __syncthreads();  // sync2: B buffer free (vmcnt already 0 -> cheap)
        if (i + 1 < ns) { issueA((i + 1) * BK, (i + 1) & 1); issueB((i + 1) * BK); }
        const unsigned short* As = smem + (i & 1) * ABUF;
#pragma unroll
        for (int s = 0; s < 2; s++) {
            int chunk = ((s * 4 + quad) ^ rsw) * 8;
            bf16x8 af[4];
#pragma unroll
            for (int ii = 0; ii < 4; ii++)
                af[ii] = *(const bf16x8*)(As + (wr + ii * 16 + l16) * BK + chunk);
#pragma unroll
            for (int ii = 0; ii < 4; ii++)
#pragma unroll
                for (int j = 0; j < 4; j++)
                    acc[ii][j] = __builtin_amdgcn_mfma_f32_16x16x32_bf16(
                        af[ii], bf[s][j], acc[ii][j], 0, 0, 0);
        }
    };

    issueA(0, 0);
    issueB(0);
    if constexpr (MODE != 2) {
        constexpr int NS = KMAX / BK;
#pragma unroll
        for (int i = 0; i < NS; i++) kbody(i, NS);
    } else {
        int ns = kend / BK;
        for (int i = 0; i < ns; i++) kbody(i, ns);
    }

    // ---------------- epilogue (C/D layout: col=lane&15, row=quad*4+reg) ----------------
    if constexpr (MODE == 0) {
        if (tn < 2048) {
            unsigned short* D = (tn < 1024 ? (unsigned short*)C0 : Kb);
            int cbase = tn & 1023;
#pragma unroll
            for (int i = 0; i < 4; i++) {
                int r0 = tm + wr + i * 16 + quad * 4;
#pragma unroll
                for (int j = 0; j < 4; j++) {
                    int c = cbase + wc + j * 16 + l16;
#pragma unroll
                    for (int rr = 0; rr < 4; rr++)
                        D[(size_t)(r0 + rr) * 1024 + c] = f2bf(acc[i][j][rr]);
                }
            }
        } else {
            // V region: transposed write via LDS (4 passes of 32 p-columns)
            int b = tm >> 11;
            int s0 = tm & 2047;
            unsigned short* VTb = VT + (size_t)b * (PDIM * SDIM)
                                     + (size_t)(tn - 2048) * SDIM + s0;
            const int TP = 136;
            unsigned short* T = smem;  // 32x136 shorts, reuses dead tile buffer
            __syncthreads();
#pragma unroll
            for (int p = 0; p < 4; p++) {
                int jbase = -1;
                if (wc == 0 && p == 0) jbase = 0;
                if (wc == 0 && p == 1) jbase = 2;
                if (wc == 64 && p == 2) jbase = 0;
                if (wc == 64 && p == 3) jbase = 2;
                if (jbase >= 0) {
#pragma unroll
                    for (int jj = 0; jj < 2; jj++) {
                        int j = jbase + jj;
                        int c = (wc + j * 16 + l16) - 32 * p;  // 0..31
#pragma unroll
                        for (int i = 0; i < 4; i++) {
                            int r = wr + i * 16 + quad * 4;
                            ushort4 w;
                            w.x = f2bf(acc[i][j][0]); w.y = f2bf(acc[i][j][1]);
                            w.z = f2bf(acc[i][j][2]); w.w = f2bf(acc[i][j][3]);
                            *(ushort4*)(T + c * TP + r) = w;
                        }
                    }
                }
                __syncthreads();
                {
                    int lr = tid >> 3;
                    int ck = (tid & 7) * 16;
                    bf16x8 u0 = *(const bf16x8*)(T + lr * TP + ck);
                    bf16x8 u1 = *(const bf16x8*)(T + lr * TP + ck + 8);
                    unsigned short* dst = VTb + (size_t)(32 * p + lr) * SDIM + ck;
                    *(bf16x8*)(dst) = u0;
                    *(bf16x8*)(dst + 8) = u1;
                }
                __syncthreads();
            }
        }
    } else {
#pragma unroll
        for (int i = 0; i < 4; i++) {
            int r0 = tm + wr + i * 16 + quad * 4;
#pragma unroll
            for (int j = 0; j < 4; j++) {
                int c = tn + wc + j * 16 + l16;
#pragma unroll
                for (int rr = 0; rr < 4; rr++) {
                    int r = r0 + rr;
                    if (MODE == 1 && c > r) continue;  // masked: never read downstream
                    storeC(C, (size_t)r * LDC + c, acc[i][j][rr] * alpha);
                }
            }
        }
    }
}

// ---------- in-place causal softmax on bf16 S ----------
__global__ __launch_bounds__(256) void softmax_causal(unsigned short* __restrict__ S01,
                                                      unsigned short* __restrict__ S23,
                                                      long long sS) {
    int row = blockIdx.x;
    int b = blockIdx.y;
    unsigned short* srow = (b < 2 ? S01 : S23) + (long long)(b & 1) * sS + (size_t)row * SDIM;
    int tid = threadIdx.x;
    int j0 = tid * 8;
    int valid = row + 1;
    int bound = ((row >> 7) + 1) << 7;
    bool active = j0 < valid;
    __shared__ float red[4];

    float f[8];
    if (active) {
        bf16x8 v8 = *(const bf16x8*)(srow + j0);
#pragma unroll
        for (int i = 0; i < 8; i++) f[i] = bf2f((unsigned short)v8[i]);
    }

    float m = -1e30f;
    if (active) {
#pragma unroll
        for (int i = 0; i < 8; i++) if (j0 + i < valid) m = fmaxf(m, f[i]);
    }
#pragma unroll
    for (int o = 32; o; o >>= 1) m = fmaxf(m, __shfl_xor(m, o, 64));
    if ((tid & 63) == 0) red[tid >> 6] = m;
    __syncthreads();
    m = fmaxf(fmaxf(red[0], red[1]), fmaxf(red[2], red[3]));
    __syncthreads();

    float e[8] = {0.f, 0.f, 0.f, 0.f, 0.f, 0.f, 0.f, 0.f};
    float l = 0.f;
    if (active) {
#pragma unroll
        for (int i = 0; i < 8; i++) {
            e[i] = (j0 + i < valid) ? __expf(f[i] - m) : 0.f;
            l += e[i];
        }
    }
#pragma unroll
    for (int o = 32; o; o >>= 1) l += __shfl_xor(l, o, 64);
    if ((tid & 63) == 0) red[tid >> 6] = l;
    __syncthreads();
    l = red[0] + red[1] + red[2] + red[3];
    float inv = 1.0f / l;

    if (j0 < bound) {
        bf16x8 o8;
#pragma unroll
        for (int i = 0; i < 8; i++) o8[i] = (short)f2bf(e[i] * inv);
        *(bf16x8*)(srow + j0) = o8;
    }
}

// ---------- host ----------
extern "C" void kernel_launch(void* const* d_in, const int* in_sizes, int n_in,
                              void* d_out, int out_size, void* d_ws, size_t ws_size,
                              hipStream_t stream) {
    const float* x  = (const float*)d_in[0];
    const float* Wq = (const float*)d_in[1];
    const float* Wk = (const float*)d_in[2];
    const float* Wv = (const float*)d_in[3];
    float* out = (float*)d_out;

    const size_t MS = (size_t)BDIM * SDIM;        // 8192
    const long long SS = (long long)SDIM * SDIM;  // per-batch score elems
    char* ws = (char*)d_ws;
    size_t off = 0;
    // S01 aliases Xb (Xb dead after QKV GEMM).
    unsigned short* Xb   = (unsigned short*)(ws + off);
    unsigned short* S01  = Xb;                          off += MS * DDIM * 2;           // 16 MB
    unsigned short* WT   = (unsigned short*)(ws + off); off += 3ull * DDIM * PDIM * 2;  // 6 MB
    unsigned short* Q    = (unsigned short*)(ws + off); off += MS * PDIM * 2;           // 16 MB
    unsigned short* Kb   = (unsigned short*)(ws + off); off += MS * PDIM * 2;           // 16 MB
    unsigned short* VT   = (unsigned short*)(ws + off); off += MS * PDIM * 2;           // 16 MB
    unsigned short* S23  = (unsigned short*)(ws + off); off += 2ull * SS * 2;           // 16 MB
    // total ~86 MB

    // 1. fused prep: cast x -> bf16  +  transpose/cast weights
    prep_kernel<<<4096 + 3072, 256, 0, stream>>>(x, Wq, Wk, Wv, Xb, WT);

    // 2. fused QKV projection -> Q, Kb, VT(transposed)   (1536 blocks)
    gemm_bt<DDIM, DDIM, PDIM, DDIM, 0, unsigned short>
        <<<dim3(3 * PDIM / 128, MS / 128, 1), 256, 0, stream>>>(
        Xb, Xb, 0, WT, 0, Q, Q, 0, Kb, VT, 1.0f);

    const long long sQ = (long long)SDIM * PDIM;   // per-batch Q/K/VT stride
    const float alpha = 1.0f / 32.0f;              // 1/sqrt(P)

    // 3. scores: packed lower-triangle grid (136 tiles) x 4 batches (544 blocks, all co-resident)
    gemm_bt<PDIM, PDIM, SDIM, PDIM, 1, unsigned short>
        <<<dim3(136, 1, BDIM), 256, 0, stream>>>(
        Q, Q + 2 * sQ, sQ, Kb, sQ, S01, S23, SS, nullptr, nullptr, alpha);

    // 4. in-place softmax (S -> P, bf16)
    softmax_causal<<<dim3(SDIM, BDIM), 256, 0, stream>>>(S01, S23, SS);

    // 5. PV: out_b = P_b @ VT_b^T, causal K clamp, big tiles dispatched first
    const long long sOut = (long long)SDIM * PDIM;
    gemm_bt<SDIM, SDIM, PDIM, SDIM, 2, float>
        <<<dim3(PDIM / 128, SDIM / 128, BDIM), 256, 0, stream>>>(
        S01, S23, SS, VT, sQ, out, out + 2 * sOut, sOut, nullptr, nullptr, 1.0f);
}